// Round 5
// baseline (2270.779 us; speedup 1.0000x reference)
//
#include <hip/hip_runtime.h>
#include <math.h>

#define NN 325
#define BB 32
#define NB (NN*BB)            // 10400
#define CCOMB 68
#define TENC 6
#define TDEC 12
#define PLANE (NB*CCOMB)      // 707200 f16 elements (plane0)
#define WSET 65472            // fp32 Weff: Wzr(340x128)+Wc(340x64)+bzr(128)+bc(64)
#define WT_SET (192*352)      // f16 transposed weights per set
#define M_SET (325*192)       // Mzr[325][128] + Mc[325][64]
#define G16_MAT (384*352)
#define AST 356               // Aproj LDS row stride (f16)

typedef _Float16 f16;
typedef f16 f16x4 __attribute__((ext_vector_type(4)));
typedef f16 f16x8 __attribute__((ext_vector_type(8)));
typedef float f32x4 __attribute__((ext_vector_type(4)));

static constexpr float ALPHA = 0.05f;
static constexpr float BETA  = 0.95f;
static constexpr float GAMMA = 0.95f;
static constexpr float ISQ2  = 0.7071067811865476f;

// ---------------- workspace offsets (floats) ----------------
static constexpr size_t OFF_G    = 0;                        // 2*NN*NN = 211250
static constexpr size_t OFF_RS   = OFF_G + 2ull*NN*NN;       // 650
static constexpr size_t OFF_RV   = OFF_RS + 650;             // 1300
static constexpr size_t OFF_WEFF = OFF_RV + 1300;            // 3*WSET
static constexpr size_t OFF_WT   = OFF_WEFF + 3ull*WSET;     // 3*WT_SET f16
static constexpr size_t OFF_G16  = OFF_WT + (3ull*WT_SET)/2; // 4*G16_MAT f16
static constexpr size_t OFF_M    = OFF_G16 + (4ull*G16_MAT)/2;
static constexpr size_t OFF_TV   = OFF_M + 3ull*M_SET;       // 576
static constexpr size_t OFF_XS   = OFF_TV + 576;             // 2*6*NB*4 f16
static constexpr size_t OFF_P0   = OFF_XS + (2ull*TENC*NB*4)/2;  // 4*PLANE f16
static constexpr size_t OFF_ZR   = OFF_P0 + (4ull*PLANE)/2;      // 2*NB*64 fp32 (G2 alias)
static constexpr size_t OFF_HENC = OFF_ZR + 2ull*NB*64;
static constexpr size_t OFF_HDEC = OFF_HENC + 2ull*NB*64;
static constexpr size_t OFF_YS   = OFF_HDEC + (size_t)NB*64;

__device__ inline unsigned pk2(float a, float b) {
    union { f16 h[2]; unsigned u; } x;
    x.h[0] = (f16)a; x.h[1] = (f16)b; return x.u;
}
__device__ inline unsigned pk2h(f16 a, f16 b) {
    union { f16 h[2]; unsigned u; } x;
    x.h[0] = a; x.h[1] = b; return x.u;
}
__device__ inline f16x8 ld8_lds(const f16* p) {   // 8B-aligned LDS read (2x b64)
    f16x4 lo = *(const f16x4*)p;
    f16x4 hi = *(const f16x4*)(p + 4);
    f16x8 r;
    r[0]=lo[0]; r[1]=lo[1]; r[2]=lo[2]; r[3]=lo[3];
    r[4]=hi[0]; r[5]=hi[1]; r[6]=hi[2]; r[7]=hi[3];
    return r;
}
__device__ inline f16x8 ldp0(const f16* p0, int v, int col) {
    f16x8 z = {};
    if (col < 2176 && v < NN) z = *(const f16x8*)(p0 + (size_t)v*2176 + col);
    return z;
}

// ---------------- prep ----------------
__global__ void k_sums(const float* __restrict__ adj, float* rs, float* cs) {
    int v = blockIdx.x; int t = threadIdx.x;
    float sr = 0.f, sc = 0.f;
    for (int w = t; w < NN; w += 64) { sr += adj[v*NN + w]; sc += adj[w*NN + v]; }
    for (int o = 32; o > 0; o >>= 1) { sr += __shfl_down(sr, o); sc += __shfl_down(sc, o); }
    if (t == 0) { rs[v] = sr + 1.0f; cs[v] = sc + 1.0f; }
}

__global__ void k_buildG(const float* __restrict__ adj, const float* __restrict__ P,
                         const float* __restrict__ rs, const float* __restrict__ cs,
                         float* __restrict__ G) {
    int idx = blockIdx.x*256 + threadIdx.x;
    if (idx >= NN*NN) return;
    int w = idx / NN, v = idx % NN;
    float d = (v == w) ? 1.0f : 0.0f;
    float a1  = (adj[v*NN + w] + d) / rs[v];
    float a1t = (adj[w*NN + v] + d) / cs[v];
    float p = P[v*NN + w];
    G[idx]         = BETA*a1  + GAMMA*p;   // G_A[n=w][v]
    G[NN*NN + idx] = BETA*a1t + GAMMA*p;   // G_T[n=w][v]
}

__global__ __launch_bounds__(256) void k_gg(const float* __restrict__ G, float* __restrict__ G2) {
    int g = blockIdx.z;
    const float* A = G + (size_t)g*NN*NN;
    float* C = G2 + (size_t)g*NN*NN;
    int n0 = blockIdx.y*32, j0 = blockIdx.x*32;
    int tx = threadIdx.x & 31, ty = threadIdx.x >> 5;
    __shared__ float As[32][33];
    __shared__ float Bs[32][33];
    float acc[4] = {};
    for (int k0 = 0; k0 < NN; k0 += 32) {
        for (int l = threadIdx.x; l < 32*32; l += 256) {
            int i = l >> 5, kk = l & 31;
            int n = n0 + i, k = k0 + kk;
            As[i][kk] = (n < NN && k < NN) ? A[(size_t)n*NN + k] : 0.0f;
            int j = j0 + kk;
            Bs[i][kk] = (k0 + i < NN && j < NN) ? A[(size_t)(k0+i)*NN + j] : 0.0f;
        }
        __syncthreads();
        #pragma unroll 8
        for (int kk = 0; kk < 32; kk++) {
            float bv = Bs[kk][tx];
            #pragma unroll
            for (int i = 0; i < 4; i++) acc[i] = fmaf(As[ty + 8*i][kk], bv, acc[i]);
        }
        __syncthreads();
    }
    #pragma unroll
    for (int i = 0; i < 4; i++) {
        int n = n0 + ty + 8*i, j = j0 + tx;
        if (n < NN && j < NN) C[(size_t)n*NN + j] = acc[i];
    }
}

// G16[m][384][352] f16: m = g*2+s ; s=0: alpha*I+G ; s=1: alpha*I+alpha*G+G2
__global__ void k_g16(const float* __restrict__ G, const float* __restrict__ G2,
                      f16* __restrict__ G16) {
    int idx = blockIdx.x*256 + threadIdx.x;
    if (idx >= 4*G16_MAT) return;
    int m = idx / G16_MAT;
    int rem = idx - m*G16_MAT;
    int n = rem / 352, v = rem - n*352;
    int g = m >> 1, s = m & 1;
    float val = 0.0f;
    if (n < NN && v < NN) {
        float gv = G[(size_t)g*NN*NN + n*NN + v];
        float d = (n == v) ? ALPHA : 0.0f;
        val = (s == 0) ? (gv + d)
                       : (G2[(size_t)g*NN*NN + n*NN + v] + ALPHA*gv + d);
    }
    G16[idx] = (f16)val;
}

__global__ void k_rowsum(const float* __restrict__ G, const float* __restrict__ G2,
                         float* __restrict__ rv) {
    int row = blockIdx.x;           // 0..649
    int g = row / NN, n = row - g*NN;
    int t = threadIdx.x;
    float s1 = 0.f, s2 = 0.f;
    for (int v = t; v < NN; v += 64) {
        s1 += G[(size_t)g*NN*NN + n*NN + v];
        s2 += G2[(size_t)g*NN*NN + n*NN + v];
    }
    for (int o = 32; o > 0; o >>= 1) { s1 += __shfl_down(s1, o); s2 += __shfl_down(s2, o); }
    if (t == 0) {
        rv[(g*2 + 0)*NN + n] = ALPHA + s1;
        rv[(g*2 + 1)*NN + n] = ALPHA + ALPHA*s1 + s2;
    }
}

// 3 weight sets in one launch: blockIdx.y selects set
__global__ void k_weff3(const float* __restrict__ W0, const float* __restrict__ b0,
                        const float* __restrict__ W1, const float* __restrict__ b1,
                        const float* __restrict__ W2, const float* __restrict__ b2,
                        float* __restrict__ WeffAll) {
    int s = blockIdx.y;
    const float* W = (s == 0) ? W0 : (s == 1) ? W1 : W2;
    const float* b = (s == 0) ? b0 : (s == 1) ? b1 : b2;
    float* Wset = WeffAll + (size_t)s*WSET;
    float* Wzr = Wset;            // 340x128
    float* Wc  = Wset + 43520;    // 340x64
    float* bzr = Wset + 65280;
    float* bc  = Wset + 65408;
    int tid = blockIdx.x*256 + threadIdx.x;
    if (tid < 340*192) {
        int k = tid / 192, col = tid % 192;
        int g = col >> 6, oo = col & 63;
        const float* Wa = W + (2*g)*204*64;
        const float* Wb = W + (2*g+1)*204*64;
        float val;
        if (k < 68)       val = Wa[k*64+oo] + Wb[k*64+oo];
        else if (k < 204) val = Wa[k*64+oo];
        else              val = Wb[(k-136)*64+oo];
        if (g < 2) Wzr[k*128 + g*64 + oo] = val;
        else       Wc[k*64 + oo] = val;
    }
    if (blockIdx.x == 0 && threadIdx.x < 192) {
        int col = threadIdx.x, g = col >> 6, oo = col & 63;
        float bv = b[(2*g)*64+oo] + b[(2*g+1)*64+oo];
        if (g < 2) bzr[col] = bv; else bc[oo] = bv;
    }
}

__global__ void k_wt3(const float* __restrict__ WeffAll, f16* __restrict__ WtAll) {
    int s = blockIdx.y;
    const float* Weff = WeffAll + (size_t)s*WSET;
    f16* Wt = WtAll + (size_t)s*WT_SET;
    int idx = blockIdx.x*256 + threadIdx.x;
    if (idx >= 192*352) return;
    int o = idx / 352, k = idx - o*352;
    float v = 0.0f;
    if (k < 340) {
        int p = k / 68, c = k - p*68;
        if (c != 3) v = (o < 128) ? Weff[k*128 + o] : Weff[43520 + k*64 + (o - 128)];
    }
    Wt[idx] = (f16)v;
}

__global__ void k_M3(const float* __restrict__ WeffAll, const float* __restrict__ rv,
                     float* __restrict__ MAll) {
    int s = blockIdx.y;
    const float* Weff = WeffAll + (size_t)s*WSET;
    float* M = MAll + (size_t)s*M_SET;
    int idx = blockIdx.x*256 + threadIdx.x;
    if (idx >= 325*192) return;
    int n = idx / 192, q = idx - n*192;
    float acc;
    if (q < 128) {
        int o = q;
        acc = Weff[3*128 + o];
        #pragma unroll
        for (int p = 1; p <= 4; p++)
            acc += rv[(p-1)*NN + n] * Weff[(p*68 + 3)*128 + o];
        M[(size_t)n*128 + o] = acc;
    } else {
        int o = q - 128;
        acc = Weff[43520 + 3*64 + o];
        #pragma unroll
        for (int p = 1; p <= 4; p++)
            acc += rv[(p-1)*NN + n] * Weff[43520 + (p*68 + 3)*64 + o];
        M[325*128 + (size_t)n*64 + o] = acc;
    }
}

__global__ void k_tv(const float* __restrict__ st, float* __restrict__ tv) {
    int idx = blockIdx.x*256 + threadIdx.x;
    if (idx >= 18*32) return;
    int b = idx & 31, t = idx >> 5;
    float v;
    if (t < 6) {
        float hour   = (st[b*48 + 24 + 2*t] + 0.5f) * 23.0f;
        float minute = (st[b*48 + 36 + 2*t] + 0.5f) * 59.0f;
        v = floorf((hour*60.0f + minute) / 5.0f);
    } else {
        int td = t - 6;
        v = floorf((st[b*48 + 24 + td] + 0.5f) * 6.0f);
    }
    tv[idx] = v;
}

__global__ void k_xs16(const float* __restrict__ x, f16* __restrict__ xs) {
    int idx = blockIdx.x*256 + threadIdx.x;
    if (idx >= 2*TENC*NB*4) return;
    int c = idx & 3;
    int r = (idx >> 2) % NB;
    int t = (idx / (4*NB)) % TENC;
    int e = idx / (4*NB*TENC);
    int n = r / BB, b = r % BB;
    float val = 0.0f;
    if (c < 3) {
        float xe = x[((b*3 + c)*NN + n)*12 + 2*t];
        float xo = x[((b*3 + c)*NN + n)*12 + 2*t + 1];
        val = (e == 0) ? (xe - xo)*ISQ2 : (xe + xo)*ISQ2;
    }
    xs[idx] = (f16)val;
}

__global__ void k_initH(const float* __restrict__ H1_0, const float* __restrict__ H2_0,
                        float* __restrict__ Henc) {
    int idx = blockIdx.x*256 + threadIdx.x;
    if (idx >= 2*NB*64) return;
    int k = idx & 63;
    int r = (idx >> 6) % NB;
    int e = idx / (NB*64);
    int n = r / BB, b = r % BB;
    const float* src = e ? H2_0 : H1_0;
    Henc[idx] = src[((size_t)b*NN + n)*64 + k];
}

// plane0 buf0 init: [x0(3) | 0 | H0(64)] f16 for both encoders
__global__ void k_init0(const f16* __restrict__ xs, const float* __restrict__ H1_0,
                        const float* __restrict__ H2_0, f16* __restrict__ p0all) {
    int idx = blockIdx.x*256 + threadIdx.x;
    if (idx >= 2*NB*CCOMB) return;
    int c = idx % CCOMB;
    int r = (idx / CCOMB) % NB;
    int e = idx / (CCOMB*NB);
    int n = r >> 5, b = r & 31;
    f16 v;
    if (c < 3)       v = xs[(size_t)e*TENC*NB*4 + (size_t)r*4 + c];
    else if (c == 3) v = (f16)0.0f;
    else {
        const float* h0 = e ? H2_0 : H1_0;
        v = (f16)h0[((size_t)b*NN + n)*64 + (c-4)];
    }
    p0all[(size_t)(e*2 + 0)*PLANE + (size_t)r*68 + c] = v;
}

// ---------------- fused diff+proj step ----------------
// Block: 4 nodes = 128 rows. Phase A: D[16][2176] = G'[4m][4n] @ plane0 -> LDS Aproj.
// Phase B: proj from Aproj (K=340 pad 352) with f16 weights; gate epilogue.
// MODE 0: z->ZR, r*H -> p0nxt H-ch, copy x-ch.  MODE 1: H update (+xn / +fc for DEC).
template<int MODE, int DEC>
__global__ __launch_bounds__(512) void k_step(
    const f16* __restrict__ G16,
    const f16* __restrict__ p0cur0, f16* __restrict__ p0nxt0, int p0estride,
    const f16* __restrict__ WtBase, int wt_stride,
    const float* __restrict__ WeffBase, int weff_stride,
    const float* __restrict__ MBase, int m_stride,
    const float* __restrict__ tv,
    float* __restrict__ ZR, float* __restrict__ Hstate,
    const f16* __restrict__ xn0, const f16* __restrict__ xn1,
    const float* __restrict__ Wfc, const float* __restrict__ bfc,
    float* __restrict__ yout)
{
    __shared__ f16 Aproj[128*AST];      // 91136 B
    __shared__ f16 Xs[8*2*32*36];       // 36864 B (per-wave double-buffered staging)
    int e = blockIdx.y;
    const f16* p0cur = p0cur0 + (size_t)e*p0estride;
    f16* p0nxt = p0nxt0 + (size_t)e*p0estride;
    const f16* Wt = WtBase + (size_t)e*wt_stride + (MODE ? 128*352 : 0);
    const float* bias = WeffBase + (size_t)e*weff_stride + (MODE ? 65408 : 65280);
    const float* Mp = MBase + (size_t)e*m_stride + (MODE ? 325*128 : 0);
    float* ZRe = ZR + (size_t)e*NB*64;
    float* Hse = Hstate + (size_t)e*NB*64;
    int n0 = blockIdx.x*4;
    int r0 = n0*32;
    int tid = threadIdx.x;
    int lane = tid & 63, w = tid >> 6;
    int l15 = lane & 15, lk = lane >> 4;

    // A-fragments for diffusion: row l15 -> (m = l15>>2, dn = l15&3)
    f16x8 agr[11];
    {
        const f16* grow = G16 + (size_t)(l15 >> 2)*G16_MAT + (size_t)(n0 + (l15 & 3))*352 + lk*8;
        #pragma unroll
        for (int ks = 0; ks < 11; ks++) agr[ks] = *(const f16x8*)(grow + ks*32);
    }
    // stage plane0 rows (p=0 region of Aproj) + zero K-pad 340..352
    for (int q = tid; q < 128*17; q += 512) {
        int row = q / 17, c4 = (q - row*17)*4;
        int r = r0 + row;
        f16x4 v = {};
        if (r < NB) v = *(const f16x4*)(p0cur + (size_t)r*68 + c4);
        *(f16x4*)(Aproj + row*AST + c4) = v;
    }
    for (int q = tid; q < 128*6; q += 512) {
        int row = q / 6, pr = q - row*6;
        *(unsigned*)(Aproj + row*AST + 340 + pr*2) = 0u;
    }

    // ---- phase A: barrier-free per-wave staging ----
    f16* wX = Xs + w*(2*32*36);
    int jq = lane & 3, v2 = lane >> 2;      // wave stages its own 32 j-cols
    int jcol = w*32 + jq*8;
    for (int jp = 0; jp < 9; jp++) {
        int jbase = jp*256;
        f16x8 sa = ldp0(p0cur, 2*v2,     jbase + jcol);
        f16x8 sb = ldp0(p0cur, 2*v2 + 1, jbase + jcol);
        {
            unsigned* L = (unsigned*)wX;
            #pragma unroll
            for (int u = 0; u < 8; u++) L[(jq*8+u)*18 + v2] = pk2h(sa[u], sb[u]);
        }
        f32x4 acc2[2] = {};
        for (int ks = 0; ks < 11; ks++) {
            if (ks < 10) {
                sa = ldp0(p0cur, (ks+1)*32 + 2*v2,     jbase + jcol);
                sb = ldp0(p0cur, (ks+1)*32 + 2*v2 + 1, jbase + jcol);
            }
            const f16* cur = wX + (ks & 1)*(32*36);
            #pragma unroll
            for (int bt = 0; bt < 2; bt++) {
                f16x8 bfr = ld8_lds(cur + (bt*16 + l15)*36 + lk*8);
                acc2[bt] = __builtin_amdgcn_mfma_f32_16x16x32_f16(agr[ks], bfr, acc2[bt], 0,0,0);
            }
            if (ks < 10) {
                unsigned* L = (unsigned*)(wX + ((ks+1) & 1)*(32*36));
                #pragma unroll
                for (int u = 0; u < 8; u++) L[(jq*8+u)*18 + v2] = pk2h(sa[u], sb[u]);
            }
        }
        // scatter D -> Aproj (cols 68..339): m = lk, dn = rr
        #pragma unroll
        for (int bt = 0; bt < 2; bt++) {
            int j = jbase + w*32 + bt*16 + l15;
            if (j < 2176) {
                int b32 = j / 68, c = j - b32*68;
                #pragma unroll
                for (int rr = 0; rr < 4; rr++)
                    Aproj[(rr*32 + b32)*AST + (lk+1)*68 + c] = (f16)acc2[bt][rr];
            }
        }
    }
    __syncthreads();

    // ---- phase B: projection from Aproj ----
    if constexpr (MODE == 0) {
        int rg = w >> 2, cg = w & 3;     // 2x4 wave grid: 64 rows x 32 cols each
        f32x4 acc[4][2] = {};
        for (int ks = 0; ks < 11; ks++) {
            f16x8 afr[4], bfr[2];
            #pragma unroll
            for (int a = 0; a < 4; a++)
                afr[a] = ld8_lds(Aproj + (rg*64 + a*16 + l15)*AST + ks*32 + lk*8);
            #pragma unroll
            for (int b = 0; b < 2; b++) {
                int o = cg*32 + b*16 + l15;
                bfr[b] = *(const f16x8*)(Wt + (size_t)o*352 + ks*32 + lk*8);
            }
            #pragma unroll
            for (int a = 0; a < 4; a++)
                #pragma unroll
                for (int b = 0; b < 2; b++)
                    acc[a][b] = __builtin_amdgcn_mfma_f32_16x16x32_f16(afr[a], bfr[b], acc[a][b], 0,0,0);
        }
        #pragma unroll
        for (int a = 0; a < 4; a++) {
            #pragma unroll
            for (int b = 0; b < 2; b++) {
                int o = cg*32 + b*16 + l15;
                #pragma unroll
                for (int rr = 0; rr < 4; rr++) {
                    int r = r0 + rg*64 + a*16 + lk*4 + rr;
                    if (r >= NB) continue;
                    int n = r >> 5, b32 = r & 31;
                    float pre = acc[a][b][rr] + bias[o] + tv[b32]*Mp[(size_t)n*128 + o];
                    float sg = 1.0f / (1.0f + expf(-pre));
                    if (o < 64) ZRe[(size_t)r*64 + o] = sg;
                    else p0nxt[(size_t)r*68 + 4 + (o-64)] =
                             (f16)(sg * Hse[(size_t)r*64 + (o-64)]);
                }
            }
        }
        // copy x/t channels cur -> nxt (xin unchanged within step)
        for (int q = tid; q < 256; q += 512) {
            int row = q >> 1, pr = q & 1;
            int r = r0 + row;
            if (r < NB)
                *(unsigned*)(p0nxt + (size_t)r*68 + pr*2) =
                    *(const unsigned*)(p0cur + (size_t)r*68 + pr*2);
        }
    } else {
        int rg = w >> 1, cg = w & 1;     // 4x2 wave grid: 32 rows x 32 cols each
        f32x4 acc[2][2] = {};
        for (int ks = 0; ks < 11; ks++) {
            f16x8 afr[2], bfr[2];
            #pragma unroll
            for (int a = 0; a < 2; a++)
                afr[a] = ld8_lds(Aproj + (rg*32 + a*16 + l15)*AST + ks*32 + lk*8);
            #pragma unroll
            for (int b = 0; b < 2; b++) {
                int o = cg*32 + b*16 + l15;
                bfr[b] = *(const f16x8*)(Wt + (size_t)o*352 + ks*32 + lk*8);
            }
            #pragma unroll
            for (int a = 0; a < 2; a++)
                #pragma unroll
                for (int b = 0; b < 2; b++)
                    acc[a][b] = __builtin_amdgcn_mfma_f32_16x16x32_f16(afr[a], bfr[b], acc[a][b], 0,0,0);
        }
        f16* Hl = Xs;   // reuse staging LDS for H bounce (DEC fc)
        #pragma unroll
        for (int a = 0; a < 2; a++) {
            #pragma unroll
            for (int b = 0; b < 2; b++) {
                int o = cg*32 + b*16 + l15;
                #pragma unroll
                for (int rr = 0; rr < 4; rr++) {
                    int rl = rg*32 + a*16 + lk*4 + rr;
                    int r = r0 + rl;
                    if (r >= NB) continue;
                    int n = r >> 5, b32 = r & 31;
                    float pre = acc[a][b][rr] + bias[o] + tv[b32]*Mp[(size_t)n*64 + o];
                    float cv = tanhf(pre);
                    float zv = ZRe[(size_t)r*64 + o];
                    float hv = Hse[(size_t)r*64 + o];
                    float hnew = zv*hv + (1.0f - zv)*cv;
                    Hse[(size_t)r*64 + o] = hnew;
                    p0nxt[(size_t)r*68 + 4 + o] = (f16)hnew;
                    if (DEC) Hl[rl*68 + o] = (f16)hnew;
                }
            }
        }
        if constexpr (!DEC) {
            const f16* xn = e ? xn1 : xn0;
            for (int q = tid; q < 256; q += 512) {
                int row = q >> 1, pr = q & 1;
                int r = r0 + row;
                if (r < NB) {
                    unsigned val = 0;
                    if (xn) val = *(const unsigned*)(xn + (size_t)r*4 + pr*2);
                    *(unsigned*)(p0nxt + (size_t)r*68 + pr*2) = val;
                }
            }
        } else {
            __syncthreads();
            for (int q = tid; q < 384; q += 512) {
                int row = q / 3, o = q - row*3;
                int r = r0 + row;
                if (r < NB) {
                    float a = bfc[o];
                    #pragma unroll 8
                    for (int k = 0; k < 64; k++)
                        a = fmaf((float)Hl[row*68 + k], Wfc[k*3 + o], a);
                    yout[(size_t)r*3 + o] = a;
                    p0nxt[(size_t)r*68 + o] = (f16)a;
                }
            }
            for (int q = tid; q < 128; q += 512) {
                int r = r0 + q;
                if (r < NB) p0nxt[(size_t)r*68 + 3] = (f16)0.0f;
            }
        }
    }
}

// ---------------- fuse + agg via MFMA; also inits decoder plane0 ----------------
__global__ __launch_bounds__(256) void k_fuse16(const float* __restrict__ H1,
        const float* __restrict__ H2,
        const float* __restrict__ wL, const float* __restrict__ bL,
        const float* __restrict__ wH, const float* __restrict__ bH,
        const float* __restrict__ Wcam, const float* __restrict__ bcam,
        const float* __restrict__ Wagg, const float* __restrict__ bagg,
        float* __restrict__ Hdec, f16* __restrict__ Dp0) {
    int r0 = blockIdx.x * 64;
    int tid = threadIdx.x;
    int lane = tid & 63, wave = tid >> 6;
    int wm = wave >> 1, wn = wave & 1;
    int l15 = lane & 15, lk = lane >> 4;
    __shared__ f16 Al[64*264];
    __shared__ f16 Wl[64*264];
    unsigned* La = (unsigned*)Al;
    unsigned* Lw = (unsigned*)Wl;
    for (int l = tid; l < 64*64; l += 256) {
        int i = l >> 6, k = l & 63;
        int r = r0 + i;
        unsigned val = 0;
        if (r < NB) {
            int n = r >> 5;
            float h1 = H1[(size_t)r*64 + k], h2 = H2[(size_t)r*64 + k];
            float s = h1 + h2;
            val = pk2(s*wL[n*64+k] + 2.0f*bL[n*64+k], s*wH[n*64+k] + 2.0f*bH[n*64+k]);
        }
        La[i*132 + k] = val;
    }
    for (int l = tid; l < 64*32; l += 256) {
        int i = l >> 5, kp = l & 31;
        int r = r0 + i;
        unsigned v1 = 0, v2 = 0;
        if (r < NB) {
            float2 a = *(const float2*)(H1 + (size_t)r*64 + 2*kp);
            float2 b = *(const float2*)(H2 + (size_t)r*64 + 2*kp);
            v1 = pk2(a.x, a.y);
            v2 = pk2(b.x, b.y);
        }
        La[i*132 + 64 + kp] = v1;
        La[i*132 + 96 + kp] = v2;
    }
    for (int idx = tid; idx < 64*128; idx += 256) {
        int kp = idx & 63, half = (idx >> 6) & 1, o = idx >> 7;
        if (half == 0) {
            float a = 0.3f * Wcam[(size_t)(2*kp)*64 + o];
            float b = 0.3f * Wcam[(size_t)(2*kp+1)*64 + o];
            Lw[o*132 + kp] = pk2(a, b);
        } else {
            float a = 0.7f * Wagg[(size_t)(2*kp)*64 + o];
            float b = 0.7f * Wagg[(size_t)(2*kp+1)*64 + o];
            Lw[o*132 + 64 + kp] = pk2(a, b);
        }
    }
    __syncthreads();
    f32x4 acc[2][2] = {};
    for (int k0 = 0; k0 < 256; k0 += 32) {
        f16x8 afr[2], bfr[2];
        #pragma unroll
        for (int a = 0; a < 2; a++)
            afr[a] = ld8_lds(Al + (wm*32 + a*16 + l15)*264 + k0 + lk*8);
        #pragma unroll
        for (int b = 0; b < 2; b++)
            bfr[b] = ld8_lds(Wl + (wn*32 + b*16 + l15)*264 + k0 + lk*8);
        #pragma unroll
        for (int a = 0; a < 2; a++)
            #pragma unroll
            for (int b = 0; b < 2; b++)
                acc[a][b] = __builtin_amdgcn_mfma_f32_16x16x32_f16(afr[a], bfr[b], acc[a][b], 0,0,0);
    }
    #pragma unroll
    for (int a = 0; a < 2; a++) {
        #pragma unroll
        for (int b = 0; b < 2; b++) {
            int o = wn*32 + b*16 + l15;
            float bo = 0.3f*bcam[o] + 0.7f*bagg[o];
            #pragma unroll
            for (int rr = 0; rr < 4; rr++) {
                int r = r0 + wm*32 + a*16 + lk*4 + rr;
                if (r >= NB) continue;
                float val = acc[a][b][rr] + bo;
                Hdec[(size_t)r*64 + o] = val;
                Dp0[(size_t)r*68 + 4 + o] = (f16)val;
            }
        }
    }
    if (tid < 256) {
        int r = r0 + (tid >> 2);
        if (r < NB) Dp0[(size_t)r*68 + (tid & 3)] = (f16)0.0f;
    }
}

__global__ void k_out(const float* __restrict__ ys, float* __restrict__ out) {
    int idx = blockIdx.x*256 + threadIdx.x;
    if (idx >= BB*3*NN*12) return;
    int l = idx % 12;
    int n = (idx / 12) % NN;
    int o = (idx / (12*NN)) % 3;
    int b = idx / (12*NN*3);
    int q = o*12 + l;
    int t = q / 3, c = q % 3;
    out[idx] = ys[((size_t)t*NB + n*BB + b)*3 + c];
}

// ---------------- host ----------------
extern "C" void kernel_launch(void* const* d_in, const int* in_sizes, int n_in,
                              void* d_out, int out_size, void* d_ws, size_t ws_size,
                              hipStream_t stream) {
    const float* x      = (const float*)d_in[0];
    const float* st     = (const float*)d_in[1];
    const float* adj    = (const float*)d_in[2];
    const float* P      = (const float*)d_in[3];
    const float* H1_0   = (const float*)d_in[4];
    const float* H2_0   = (const float*)d_in[6];
    const float* W_encD = (const float*)d_in[8];
    const float* b_encD = (const float*)d_in[9];
    const float* W_encAD= (const float*)d_in[10];
    const float* b_encAD= (const float*)d_in[11];
    const float* W_dec  = (const float*)d_in[12];
    const float* b_dec  = (const float*)d_in[13];
    const float* W_fc   = (const float*)d_in[14];
    const float* b_fc   = (const float*)d_in[15];
    const float* W_aggH = (const float*)d_in[16];
    const float* b_aggH = (const float*)d_in[17];
    const float* W_camH = (const float*)d_in[20];
    const float* b_camH = (const float*)d_in[21];
    const float* wL     = (const float*)d_in[24];
    const float* bL     = (const float*)d_in[25];
    const float* wH     = (const float*)d_in[26];
    const float* bH     = (const float*)d_in[27];

    float* ws   = (float*)d_ws;
    float* G    = ws + OFF_G;
    float* rs   = ws + OFF_RS;
    float* cs   = rs + NN;
    float* rv   = ws + OFF_RV;
    float* Weff = ws + OFF_WEFF;
    f16*   Wt   = (f16*)(ws + OFF_WT);
    f16*   G16  = (f16*)(ws + OFF_G16);
    float* Mw   = ws + OFF_M;
    float* tv   = ws + OFF_TV;
    f16*   xs   = (f16*)(ws + OFF_XS);
    f16*   p0   = (f16*)(ws + OFF_P0);    // [e][buf][PLANE]
    float* ZR   = ws + OFF_ZR;
    float* G2   = ZR;                      // alias: prep only
    float* Henc = ws + OFF_HENC;
    float* Hdec = ws + OFF_HDEC;
    float* ys   = ws + OFF_YS;

    // ---- prep ----
    k_sums<<<NN, 64, 0, stream>>>(adj, rs, cs);
    k_buildG<<<(NN*NN + 255)/256, 256, 0, stream>>>(adj, P, rs, cs, G);
    k_gg<<<dim3(11,11,2), 256, 0, stream>>>(G, G2);
    k_g16<<<(4*G16_MAT + 255)/256, 256, 0, stream>>>(G, G2, G16);
    k_rowsum<<<650, 64, 0, stream>>>(G, G2, rv);
    k_weff3<<<dim3(255,3), 256, 0, stream>>>(W_encD, b_encD, W_encAD, b_encAD,
                                             W_dec, b_dec, Weff);
    k_wt3<<<dim3((192*352 + 255)/256, 3), 256, 0, stream>>>(Weff, Wt);
    k_M3<<<dim3((325*192 + 255)/256, 3), 256, 0, stream>>>(Weff, rv, Mw);
    k_tv<<<3, 256, 0, stream>>>(st, tv);
    k_xs16<<<(2*TENC*NB*4 + 255)/256, 256, 0, stream>>>(x, xs);
    k_initH<<<(2*NB*64 + 255)/256, 256, 0, stream>>>(H1_0, H2_0, Henc);
    k_init0<<<(2*NB*CCOMB + 255)/256, 256, 0, stream>>>(xs, H1_0, H2_0, p0);

    int par = 0;
    // ---- encoders (E=2): per step: fused(diff+proj0), fused(diff+proj1) ----
    for (int t = 0; t < TENC; t++) {
        const f16* xn0 = (t < TENC-1) ? (xs + (size_t)(t+1)*NB*4) : nullptr;
        const f16* xn1 = (t < TENC-1) ? (xs + (size_t)(TENC + t+1)*NB*4) : nullptr;
        k_step<0,0><<<dim3(82,2), 512, 0, stream>>>(G16,
            p0 + (size_t)par*PLANE, p0 + (size_t)(par^1)*PLANE, 2*PLANE,
            Wt, WT_SET, Weff, WSET, Mw, M_SET, tv + (size_t)t*32,
            ZR, Henc, nullptr, nullptr, nullptr, nullptr, nullptr);
        par ^= 1;
        k_step<1,0><<<dim3(82,2), 512, 0, stream>>>(G16,
            p0 + (size_t)par*PLANE, p0 + (size_t)(par^1)*PLANE, 2*PLANE,
            Wt, WT_SET, Weff, WSET, Mw, M_SET, tv + (size_t)t*32,
            ZR, Henc, xn0, xn1, nullptr, nullptr, nullptr);
        par ^= 1;
    }

    // ---- fuse + decoder plane0 init (par==0 here) ----
    k_fuse16<<<163, 256, 0, stream>>>(Henc, Henc + (size_t)NB*64,
                                      wL, bL, wH, bH, W_camH, b_camH, W_aggH, b_aggH,
                                      Hdec, p0);

    // ---- decoder (E=1, weight set 2) ----
    for (int t = 0; t < TDEC; t++) {
        const float* tvt = tv + (size_t)(6 + t)*32;
        k_step<0,0><<<dim3(82,1), 512, 0, stream>>>(G16,
            p0 + (size_t)par*PLANE, p0 + (size_t)(par^1)*PLANE, 0,
            Wt + 2*WT_SET, 0, Weff + 2*WSET, 0, Mw + 2*M_SET, 0, tvt,
            ZR, Hdec, nullptr, nullptr, nullptr, nullptr, nullptr);
        par ^= 1;
        k_step<1,1><<<dim3(82,1), 512, 0, stream>>>(G16,
            p0 + (size_t)par*PLANE, p0 + (size_t)(par^1)*PLANE, 0,
            Wt + 2*WT_SET, 0, Weff + 2*WSET, 0, Mw + 2*M_SET, 0, tvt,
            ZR, Hdec, nullptr, nullptr, W_fc, b_fc, ys + (size_t)t*NB*3);
        par ^= 1;
    }

    k_out<<<(BB*3*NN*12 + 255)/256, 256, 0, stream>>>(ys, (float*)d_out);
}

// Round 6
// 1391.241 us; speedup vs baseline: 1.6322x; 1.6322x over previous
//
#include <hip/hip_runtime.h>
#include <math.h>

#define NN 325
#define BB 32
#define NB (NN*BB)            // 10400
#define TENC 6
#define TDEC 12
#define WSET 65472            // fp32 Weff: Wzr(340x128)+Wc(340x64)+bzr(128)+bc(64)
#define WT_SET (192*352)      // f16 transposed weights per set
#define M_SET (325*192)       // Mzr[325][128] + Mc[325][64]
#define G16_MAT (384*352)
#define DP_B 3660800ull       // 10400*352 f16 per buf
#define DP_E 7321600ull       // 2 bufs per stream
#define PT_B 765952ull        // 2176*352 f16 per buf
#define PT_E 1531904ull

typedef _Float16 f16;
typedef f16 f16x4 __attribute__((ext_vector_type(4)));
typedef f16 f16x8 __attribute__((ext_vector_type(8)));
typedef float f32x4 __attribute__((ext_vector_type(4)));

static constexpr float ALPHA = 0.05f;
static constexpr float BETA  = 0.95f;
static constexpr float GAMMA = 0.95f;
static constexpr float ISQ2  = 0.7071067811865476f;

// ---------------- workspace offsets (floats) ----------------
static constexpr size_t OFF_G    = 0;                        // 211250
static constexpr size_t OFF_RS   = OFF_G + 2ull*NN*NN;       // 650
static constexpr size_t OFF_RV   = OFF_RS + 650;             // 1300
static constexpr size_t OFF_WEFF = OFF_RV + 1300;            // 196416
static constexpr size_t OFF_WT   = OFF_WEFF + 3ull*WSET;     // 101376
static constexpr size_t OFF_G16  = OFF_WT + (3ull*WT_SET)/2; // 270336
static constexpr size_t OFF_M    = OFF_G16 + (4ull*G16_MAT)/2;
static constexpr size_t OFF_TV   = OFF_M + 3ull*M_SET;       // 576
static constexpr size_t OFF_XS   = OFF_TV + 576;             // 249600
static constexpr size_t OFF_DP   = OFF_XS + (2ull*TENC*NB*4)/2;  // Dproj f16 [2e][2buf][10400][352]
static constexpr size_t OFF_PT   = OFF_DP + (2ull*DP_E)/2;       // P0T f16 [2e][2buf][2176][352]
static constexpr size_t OFF_ZR   = OFF_PT + (2ull*PT_E)/2;       // 2*NB*64 fp32 (G2 alias)
static constexpr size_t OFF_HENC = OFF_ZR + 2ull*NB*64;
static constexpr size_t OFF_HDEC = OFF_HENC + 2ull*NB*64;
static constexpr size_t OFF_YS   = OFF_HDEC + (size_t)NB*64;

__device__ inline unsigned pk2(float a, float b) {
    union { f16 h[2]; unsigned u; } x;
    x.h[0] = (f16)a; x.h[1] = (f16)b; return x.u;
}
__device__ inline void st4h(f16* p, float a, float b, float c, float d) {
    f16x4 v; v[0]=(f16)a; v[1]=(f16)b; v[2]=(f16)c; v[3]=(f16)d;
    *(f16x4*)p = v;
}
__device__ inline f16x8 ld8_lds(const f16* p) {
    f16x4 lo = *(const f16x4*)p;
    f16x4 hi = *(const f16x4*)(p + 4);
    f16x8 r;
    r[0]=lo[0]; r[1]=lo[1]; r[2]=lo[2]; r[3]=lo[3];
    r[4]=hi[0]; r[5]=hi[1]; r[6]=hi[2]; r[7]=hi[3];
    return r;
}

// ---------------- prep ----------------
__global__ void k_sums(const float* __restrict__ adj, float* rs, float* cs) {
    int v = blockIdx.x; int t = threadIdx.x;
    float sr = 0.f, sc = 0.f;
    for (int w = t; w < NN; w += 64) { sr += adj[v*NN + w]; sc += adj[w*NN + v]; }
    for (int o = 32; o > 0; o >>= 1) { sr += __shfl_down(sr, o); sc += __shfl_down(sc, o); }
    if (t == 0) { rs[v] = sr + 1.0f; cs[v] = sc + 1.0f; }
}

__global__ void k_buildG(const float* __restrict__ adj, const float* __restrict__ P,
                         const float* __restrict__ rs, const float* __restrict__ cs,
                         float* __restrict__ G) {
    int idx = blockIdx.x*256 + threadIdx.x;
    if (idx >= NN*NN) return;
    int w = idx / NN, v = idx % NN;
    float d = (v == w) ? 1.0f : 0.0f;
    float a1  = (adj[v*NN + w] + d) / rs[v];
    float a1t = (adj[w*NN + v] + d) / cs[v];
    float p = P[v*NN + w];
    G[idx]         = BETA*a1  + GAMMA*p;
    G[NN*NN + idx] = BETA*a1t + GAMMA*p;
}

__global__ __launch_bounds__(256) void k_gg(const float* __restrict__ G, float* __restrict__ G2) {
    int g = blockIdx.z;
    const float* A = G + (size_t)g*NN*NN;
    float* C = G2 + (size_t)g*NN*NN;
    int n0 = blockIdx.y*32, j0 = blockIdx.x*32;
    int tx = threadIdx.x & 31, ty = threadIdx.x >> 5;
    __shared__ float As[32][33];
    __shared__ float Bs[32][33];
    float acc[4] = {};
    for (int k0 = 0; k0 < NN; k0 += 32) {
        for (int l = threadIdx.x; l < 32*32; l += 256) {
            int i = l >> 5, kk = l & 31;
            int n = n0 + i, k = k0 + kk;
            As[i][kk] = (n < NN && k < NN) ? A[(size_t)n*NN + k] : 0.0f;
            int j = j0 + kk;
            Bs[i][kk] = (k0 + i < NN && j < NN) ? A[(size_t)(k0+i)*NN + j] : 0.0f;
        }
        __syncthreads();
        #pragma unroll 8
        for (int kk = 0; kk < 32; kk++) {
            float bv = Bs[kk][tx];
            #pragma unroll
            for (int i = 0; i < 4; i++) acc[i] = fmaf(As[ty + 8*i][kk], bv, acc[i]);
        }
        __syncthreads();
    }
    #pragma unroll
    for (int i = 0; i < 4; i++) {
        int n = n0 + ty + 8*i, j = j0 + tx;
        if (n < NN && j < NN) C[(size_t)n*NN + j] = acc[i];
    }
}

__global__ void k_g16(const float* __restrict__ G, const float* __restrict__ G2,
                      f16* __restrict__ G16) {
    int idx = blockIdx.x*256 + threadIdx.x;
    if (idx >= 4*G16_MAT) return;
    int m = idx / G16_MAT;
    int rem = idx - m*G16_MAT;
    int n = rem / 352, v = rem - n*352;
    int g = m >> 1, s = m & 1;
    float val = 0.0f;
    if (n < NN && v < NN) {
        float gv = G[(size_t)g*NN*NN + n*NN + v];
        float d = (n == v) ? ALPHA : 0.0f;
        val = (s == 0) ? (gv + d)
                       : (G2[(size_t)g*NN*NN + n*NN + v] + ALPHA*gv + d);
    }
    G16[idx] = (f16)val;
}

__global__ void k_rowsum(const float* __restrict__ G, const float* __restrict__ G2,
                         float* __restrict__ rv) {
    int row = blockIdx.x;
    int g = row / NN, n = row - g*NN;
    int t = threadIdx.x;
    float s1 = 0.f, s2 = 0.f;
    for (int v = t; v < NN; v += 64) {
        s1 += G[(size_t)g*NN*NN + n*NN + v];
        s2 += G2[(size_t)g*NN*NN + n*NN + v];
    }
    for (int o = 32; o > 0; o >>= 1) { s1 += __shfl_down(s1, o); s2 += __shfl_down(s2, o); }
    if (t == 0) {
        rv[(g*2 + 0)*NN + n] = ALPHA + s1;
        rv[(g*2 + 1)*NN + n] = ALPHA + ALPHA*s1 + s2;
    }
}

__global__ void k_weff3(const float* __restrict__ W0, const float* __restrict__ b0,
                        const float* __restrict__ W1, const float* __restrict__ b1,
                        const float* __restrict__ W2, const float* __restrict__ b2,
                        float* __restrict__ WeffAll) {
    int s = blockIdx.y;
    const float* W = (s == 0) ? W0 : (s == 1) ? W1 : W2;
    const float* b = (s == 0) ? b0 : (s == 1) ? b1 : b2;
    float* Wset = WeffAll + (size_t)s*WSET;
    float* Wzr = Wset;
    float* Wc  = Wset + 43520;
    float* bzr = Wset + 65280;
    float* bc  = Wset + 65408;
    int tid = blockIdx.x*256 + threadIdx.x;
    if (tid < 340*192) {
        int k = tid / 192, col = tid % 192;
        int g = col >> 6, oo = col & 63;
        const float* Wa = W + (2*g)*204*64;
        const float* Wb = W + (2*g+1)*204*64;
        float val;
        if (k < 68)       val = Wa[k*64+oo] + Wb[k*64+oo];
        else if (k < 204) val = Wa[k*64+oo];
        else              val = Wb[(k-136)*64+oo];
        if (g < 2) Wzr[k*128 + g*64 + oo] = val;
        else       Wc[k*64 + oo] = val;
    }
    if (blockIdx.x == 0 && threadIdx.x < 192) {
        int col = threadIdx.x, g = col >> 6, oo = col & 63;
        float bv = b[(2*g)*64+oo] + b[(2*g+1)*64+oo];
        if (g < 2) bzr[col] = bv; else bc[oo] = bv;
    }
}

__global__ void k_wt3(const float* __restrict__ WeffAll, f16* __restrict__ WtAll) {
    int s = blockIdx.y;
    const float* Weff = WeffAll + (size_t)s*WSET;
    f16* Wt = WtAll + (size_t)s*WT_SET;
    int idx = blockIdx.x*256 + threadIdx.x;
    if (idx >= 192*352) return;
    int o = idx / 352, k = idx - o*352;
    float v = 0.0f;
    if (k < 340) {
        int p = k / 68, c = k - p*68;
        if (c != 3) v = (o < 128) ? Weff[k*128 + o] : Weff[43520 + k*64 + (o - 128)];
    }
    Wt[idx] = (f16)v;
}

__global__ void k_M3(const float* __restrict__ WeffAll, const float* __restrict__ rv,
                     float* __restrict__ MAll) {
    int s = blockIdx.y;
    const float* Weff = WeffAll + (size_t)s*WSET;
    float* M = MAll + (size_t)s*M_SET;
    int idx = blockIdx.x*256 + threadIdx.x;
    if (idx >= 325*192) return;
    int n = idx / 192, q = idx - n*192;
    float acc;
    if (q < 128) {
        int o = q;
        acc = Weff[3*128 + o];
        #pragma unroll
        for (int p = 1; p <= 4; p++)
            acc += rv[(p-1)*NN + n] * Weff[(p*68 + 3)*128 + o];
        M[(size_t)n*128 + o] = acc;
    } else {
        int o = q - 128;
        acc = Weff[43520 + 3*64 + o];
        #pragma unroll
        for (int p = 1; p <= 4; p++)
            acc += rv[(p-1)*NN + n] * Weff[43520 + (p*68 + 3)*64 + o];
        M[325*128 + (size_t)n*64 + o] = acc;
    }
}

__global__ void k_tv(const float* __restrict__ st, float* __restrict__ tv) {
    int idx = blockIdx.x*256 + threadIdx.x;
    if (idx >= 18*32) return;
    int b = idx & 31, t = idx >> 5;
    float v;
    if (t < 6) {
        float hour   = (st[b*48 + 24 + 2*t] + 0.5f) * 23.0f;
        float minute = (st[b*48 + 36 + 2*t] + 0.5f) * 59.0f;
        v = floorf((hour*60.0f + minute) / 5.0f);
    } else {
        int td = t - 6;
        v = floorf((st[b*48 + 24 + td] + 0.5f) * 6.0f);
    }
    tv[idx] = v;
}

__global__ void k_xs16(const float* __restrict__ x, f16* __restrict__ xs) {
    int idx = blockIdx.x*256 + threadIdx.x;
    if (idx >= 2*TENC*NB*4) return;
    int c = idx & 3;
    int r = (idx >> 2) % NB;
    int t = (idx / (4*NB)) % TENC;
    int e = idx / (4*NB*TENC);
    int n = r / BB, b = r % BB;
    float val = 0.0f;
    if (c < 3) {
        float xe = x[((b*3 + c)*NN + n)*12 + 2*t];
        float xo = x[((b*3 + c)*NN + n)*12 + 2*t + 1];
        val = (e == 0) ? (xe - xo)*ISQ2 : (xe + xo)*ISQ2;
    }
    xs[idx] = (f16)val;
}

__global__ void k_initH(const float* __restrict__ H1_0, const float* __restrict__ H2_0,
                        float* __restrict__ Henc) {
    int idx = blockIdx.x*256 + threadIdx.x;
    if (idx >= 2*NB*64) return;
    int k = idx & 63;
    int r = (idx >> 6) % NB;
    int e = idx / (NB*64);
    int n = r / BB, b = r % BB;
    const float* src = e ? H2_0 : H1_0;
    Henc[idx] = src[((size_t)b*NN + n)*64 + k];
}

// Dproj init: buf0 cols 0..67 = [x|0|H0]; zero pad cols 340..351 in BOTH bufs
__global__ void k_initDP(const f16* __restrict__ xs, const float* __restrict__ H1_0,
                         const float* __restrict__ H2_0, f16* __restrict__ DP) {
    int idx = blockIdx.x*256 + threadIdx.x;
    if (idx >= 2*NB*92) return;
    int cc = idx % 92;
    int r = (idx / 92) % NB;
    int e = idx / (92*NB);
    int n = r >> 5, b = r & 31;
    f16* D0 = DP + (size_t)e*DP_E;
    if (cc < 68) {
        f16 v;
        if (cc < 3)       v = xs[(size_t)e*TENC*NB*4 + (size_t)r*4 + cc];
        else if (cc == 3) v = (f16)0.0f;
        else {
            const float* h0 = e ? H2_0 : H1_0;
            v = (f16)h0[((size_t)b*NN + n)*64 + (cc-4)];
        }
        D0[(size_t)r*352 + cc] = v;
    } else if (cc < 80) {
        D0[(size_t)r*352 + 340 + (cc-68)] = (f16)0.0f;
    } else {
        D0[DP_B + (size_t)r*352 + 340 + (cc-80)] = (f16)0.0f;
    }
}

// P0T init: buf0 full values; v-pad (v>=325) zero in BOTH bufs
__global__ void k_initPT(const f16* __restrict__ xs, const float* __restrict__ H1_0,
                         const float* __restrict__ H2_0, f16* __restrict__ PTb) {
    int idx = blockIdx.x*256 + threadIdx.x;
    if (idx >= 2*2176*352) return;
    int v = idx % 352;
    int j = (idx / 352) % 2176;
    int e = idx / (352*2176);
    f16* P0 = PTb + (size_t)e*PT_E;
    if (v >= NN) {
        P0[(size_t)j*352 + v] = (f16)0.0f;
        P0[PT_B + (size_t)j*352 + v] = (f16)0.0f;
        return;
    }
    int b = j / 68, c = j - b*68;
    f16 val;
    if (c < 3)       val = xs[(size_t)e*TENC*NB*4 + (size_t)(v*32+b)*4 + c];
    else if (c == 3) val = (f16)0.0f;
    else {
        const float* h0 = e ? H2_0 : H1_0;
        val = (f16)h0[((size_t)b*NN + v)*64 + (c-4)];
    }
    P0[(size_t)j*352 + v] = val;
}

// -------- diffusion, LDS-free: D^T[j][R] = sum_v P0T[j][v] * G16[R][v] --------
// grid (34 j-tiles, 21 R-tiles, E); block 256 (4 waves 2x2), wave 32j x 32R
__global__ __launch_bounds__(256) void k_diffT(const f16* __restrict__ G16,
        const f16* __restrict__ XB, f16* __restrict__ DB) {
    int e = blockIdx.z;
    const f16* X = XB + (size_t)e*PT_E;
    f16* D = DB + (size_t)e*DP_E;
    int j0 = blockIdx.x*64, R0 = blockIdx.y*64;
    int lane = threadIdx.x & 63, w = threadIdx.x >> 6;
    int wm = w >> 1, wn = w & 1;
    int l15 = lane & 15, lk = lane >> 4;
    const f16* ap[2];
    #pragma unroll
    for (int a = 0; a < 2; a++)
        ap[a] = X + (size_t)(j0 + wm*32 + a*16 + l15)*352;
    const f16* bp[2]; int mv[2], nv[2];
    #pragma unroll
    for (int bt = 0; bt < 2; bt++) {
        int R = R0 + wn*32 + bt*16 + l15;
        int ok = (R < 1300);
        int Rc = ok ? R : 0;
        int m = Rc / 325, n = Rc - m*325;
        mv[bt] = ok ? m : -1; nv[bt] = n;
        bp[bt] = G16 + (size_t)m*G16_MAT + (size_t)n*352;
    }
    f32x4 acc[2][2] = {};
    #pragma unroll
    for (int k0 = 0; k0 < 352; k0 += 32) {
        f16x8 af[2], bf[2];
        #pragma unroll
        for (int a = 0; a < 2; a++) af[a] = *(const f16x8*)(ap[a] + k0 + lk*8);
        #pragma unroll
        for (int bt = 0; bt < 2; bt++) bf[bt] = *(const f16x8*)(bp[bt] + k0 + lk*8);
        #pragma unroll
        for (int a = 0; a < 2; a++)
            #pragma unroll
            for (int bt = 0; bt < 2; bt++)
                acc[a][bt] = __builtin_amdgcn_mfma_f32_16x16x32_f16(af[a], bf[bt], acc[a][bt], 0,0,0);
    }
    // D^T: col(l15)=R, rows(lk*4+rr)=j ; j%4 runs never cross a b-boundary (68%4==0)
    #pragma unroll
    for (int bt = 0; bt < 2; bt++) {
        if (mv[bt] < 0) continue;
        int m = mv[bt], n = nv[bt];
        #pragma unroll
        for (int a = 0; a < 2; a++) {
            int jb = j0 + wm*32 + a*16 + lk*4;
            int b = jb / 68, c = jb - b*68;
            f16* dst = D + (size_t)(n*32 + b)*352 + (m+1)*68 + c;
            st4h(dst, acc[a][bt][0], acc[a][bt][1], acc[a][bt][2], acc[a][bt][3]);
        }
    }
}

// -------- projection, LDS-free: out^T[o][r] = sum_k Wt[o][k] * Dproj[r][k] --------
// MODE 0: grid (2,163,E): o-block0 -> z->ZR + x-copy ; o-block1 -> r*H -> next bufs
// MODE 1: grid (1,163,E): H update -> Hstate + next bufs (+ xn for encoder)
template<int MODE>
__global__ __launch_bounds__(256) void k_projT(
        const f16* __restrict__ WtB, int wt_str,
        const float* __restrict__ biasB, int bias_str,
        const float* __restrict__ MB, int m_str,
        const float* __restrict__ tv,
        const f16* __restrict__ DcurB, f16* __restrict__ DnxtB, f16* __restrict__ PTnxtB,
        float* __restrict__ ZRB, float* __restrict__ HstB,
        const f16* __restrict__ xn0, const f16* __restrict__ xn1) {
    constexpr int OW = (MODE == 0) ? 128 : 64;
    int e = blockIdx.z;
    const f16* Wt = WtB + (size_t)e*wt_str + (MODE ? 128*352 : 0);
    const float* bias = biasB + (size_t)e*bias_str + (MODE ? 65408 : 65280);
    const float* M = MB + (size_t)e*m_str + (MODE ? 325*128 : 0);
    const f16* Dc = DcurB + (size_t)e*DP_E;
    f16* Dn = DnxtB + (size_t)e*DP_E;
    f16* PT = PTnxtB + (size_t)e*PT_E;
    float* ZR = ZRB + (size_t)e*NB*64;
    float* Hs = HstB + (size_t)e*NB*64;
    int o0 = (MODE == 0) ? blockIdx.x*64 : 0;
    int r0 = blockIdx.y*64;
    int lane = threadIdx.x & 63, w = threadIdx.x >> 6;
    int wm = w >> 1, wn = w & 1;
    int l15 = lane & 15, lk = lane >> 4;
    const f16* ap[2]; const f16* bp[2];
    #pragma unroll
    for (int a = 0; a < 2; a++) ap[a] = Wt + (size_t)(o0 + wm*32 + a*16 + l15)*352;
    #pragma unroll
    for (int bt = 0; bt < 2; bt++) bp[bt] = Dc + (size_t)(r0 + wn*32 + bt*16 + l15)*352;
    f32x4 acc[2][2] = {};
    #pragma unroll
    for (int k0 = 0; k0 < 352; k0 += 32) {
        f16x8 af[2], bf[2];
        #pragma unroll
        for (int a = 0; a < 2; a++) af[a] = *(const f16x8*)(ap[a] + k0 + lk*8);
        #pragma unroll
        for (int bt = 0; bt < 2; bt++) bf[bt] = *(const f16x8*)(bp[bt] + k0 + lk*8);
        #pragma unroll
        for (int a = 0; a < 2; a++)
            #pragma unroll
            for (int bt = 0; bt < 2; bt++)
                acc[a][bt] = __builtin_amdgcn_mfma_f32_16x16x32_f16(af[a], bf[bt], acc[a][bt], 0,0,0);
    }
    #pragma unroll
    for (int bt = 0; bt < 2; bt++) {
        int r = r0 + wn*32 + bt*16 + l15;
        if (r < NB) {
            int n = r >> 5, b = r & 31;
            float tvb = tv[b];
            #pragma unroll
            for (int a = 0; a < 2; a++) {
                int ob = o0 + wm*32 + a*16 + lk*4;
                float4 bs = *(const float4*)(bias + ob);
                float4 ms = *(const float4*)(M + (size_t)n*OW + ob);
                float p0 = acc[a][bt][0] + bs.x + tvb*ms.x;
                float p1 = acc[a][bt][1] + bs.y + tvb*ms.y;
                float p2 = acc[a][bt][2] + bs.z + tvb*ms.z;
                float p3 = acc[a][bt][3] + bs.w + tvb*ms.w;
                if constexpr (MODE == 0) {
                    float s0 = 1.0f/(1.0f+expf(-p0)), s1 = 1.0f/(1.0f+expf(-p1));
                    float s2 = 1.0f/(1.0f+expf(-p2)), s3 = 1.0f/(1.0f+expf(-p3));
                    if (ob < 64) {
                        *(float4*)(ZR + (size_t)r*64 + ob) = make_float4(s0,s1,s2,s3);
                    } else {
                        int oh = ob - 64;
                        float4 h4 = *(const float4*)(Hs + (size_t)r*64 + oh);
                        float g0 = s0*h4.x, g1 = s1*h4.y, g2 = s2*h4.z, g3 = s3*h4.w;
                        st4h(Dn + (size_t)r*352 + 4 + oh, g0, g1, g2, g3);
                        size_t pb = (size_t)(b*68 + 4 + oh)*352 + n;
                        PT[pb]       = (f16)g0;
                        PT[pb + 352] = (f16)g1;
                        PT[pb + 704] = (f16)g2;
                        PT[pb + 1056]= (f16)g3;
                    }
                } else {
                    float4 z4 = *(const float4*)(ZR + (size_t)r*64 + ob);
                    float4 h4 = *(const float4*)(Hs + (size_t)r*64 + ob);
                    float h0 = z4.x*h4.x + (1.0f - z4.x)*tanhf(p0);
                    float h1 = z4.y*h4.y + (1.0f - z4.y)*tanhf(p1);
                    float h2 = z4.z*h4.z + (1.0f - z4.z)*tanhf(p2);
                    float h3 = z4.w*h4.w + (1.0f - z4.w)*tanhf(p3);
                    *(float4*)(Hs + (size_t)r*64 + ob) = make_float4(h0,h1,h2,h3);
                    st4h(Dn + (size_t)r*352 + 4 + ob, h0, h1, h2, h3);
                    size_t pb = (size_t)(b*68 + 4 + ob)*352 + n;
                    PT[pb]       = (f16)h0;
                    PT[pb + 352] = (f16)h1;
                    PT[pb + 704] = (f16)h2;
                    PT[pb + 1056]= (f16)h3;
                }
            }
        }
    }
    // x/t channels into next buffers
    if constexpr (MODE == 0) {
        if (blockIdx.x == 0) {
            int row = threadIdx.x >> 2, q = threadIdx.x & 3;
            int r = r0 + row;
            if (r < NB) {
                f16 v = Dc[(size_t)r*352 + q];
                Dn[(size_t)r*352 + q] = v;
                PT[(size_t)((r & 31)*68 + q)*352 + (r >> 5)] = v;
            }
        }
    } else {
        const f16* xn = e ? xn1 : xn0;
        if (xn) {
            int row = threadIdx.x >> 2, q = threadIdx.x & 3;
            int r = r0 + row;
            if (r < NB) {
                f16 v = (q < 3) ? xn[(size_t)r*4 + q] : (f16)0.0f;
                Dn[(size_t)r*352 + q] = v;
                PT[(size_t)((r & 31)*68 + q)*352 + (r >> 5)] = v;
            }
        }
    }
}

// -------- fuse + agg via MFMA; inits decoder Dproj/P0T buf0 --------
__global__ __launch_bounds__(256) void k_fuse16(const float* __restrict__ H1,
        const float* __restrict__ H2,
        const float* __restrict__ wL, const float* __restrict__ bL,
        const float* __restrict__ wH, const float* __restrict__ bH,
        const float* __restrict__ Wcam, const float* __restrict__ bcam,
        const float* __restrict__ Wagg, const float* __restrict__ bagg,
        float* __restrict__ Hdec, f16* __restrict__ Dn, f16* __restrict__ PTn) {
    int r0 = blockIdx.x * 64;
    int tid = threadIdx.x;
    int lane = tid & 63, wave = tid >> 6;
    int wm = wave >> 1, wn = wave & 1;
    int l15 = lane & 15, lk = lane >> 4;
    __shared__ f16 Al[64*264];
    __shared__ f16 Wl[64*264];
    unsigned* La = (unsigned*)Al;
    unsigned* Lw = (unsigned*)Wl;
    for (int l = tid; l < 64*64; l += 256) {
        int i = l >> 6, k = l & 63;
        int r = r0 + i;
        unsigned val = 0;
        if (r < NB) {
            int n = r >> 5;
            float h1 = H1[(size_t)r*64 + k], h2 = H2[(size_t)r*64 + k];
            float s = h1 + h2;
            val = pk2(s*wL[n*64+k] + 2.0f*bL[n*64+k], s*wH[n*64+k] + 2.0f*bH[n*64+k]);
        }
        La[i*132 + k] = val;
    }
    for (int l = tid; l < 64*32; l += 256) {
        int i = l >> 5, kp = l & 31;
        int r = r0 + i;
        unsigned v1 = 0, v2 = 0;
        if (r < NB) {
            float2 a = *(const float2*)(H1 + (size_t)r*64 + 2*kp);
            float2 b = *(const float2*)(H2 + (size_t)r*64 + 2*kp);
            v1 = pk2(a.x, a.y);
            v2 = pk2(b.x, b.y);
        }
        La[i*132 + 64 + kp] = v1;
        La[i*132 + 96 + kp] = v2;
    }
    for (int idx = tid; idx < 64*128; idx += 256) {
        int kp = idx & 63, half = (idx >> 6) & 1, o = idx >> 7;
        if (half == 0) {
            float a = 0.3f * Wcam[(size_t)(2*kp)*64 + o];
            float b = 0.3f * Wcam[(size_t)(2*kp+1)*64 + o];
            Lw[o*132 + kp] = pk2(a, b);
        } else {
            float a = 0.7f * Wagg[(size_t)(2*kp)*64 + o];
            float b = 0.7f * Wagg[(size_t)(2*kp+1)*64 + o];
            Lw[o*132 + 64 + kp] = pk2(a, b);
        }
    }
    __syncthreads();
    f32x4 acc[2][2] = {};
    for (int k0 = 0; k0 < 256; k0 += 32) {
        f16x8 afr[2], bfr[2];
        #pragma unroll
        for (int a = 0; a < 2; a++)
            afr[a] = ld8_lds(Al + (wm*32 + a*16 + l15)*264 + k0 + lk*8);
        #pragma unroll
        for (int b = 0; b < 2; b++)
            bfr[b] = ld8_lds(Wl + (wn*32 + b*16 + l15)*264 + k0 + lk*8);
        #pragma unroll
        for (int a = 0; a < 2; a++)
            #pragma unroll
            for (int b = 0; b < 2; b++)
                acc[a][b] = __builtin_amdgcn_mfma_f32_16x16x32_f16(afr[a], bfr[b], acc[a][b], 0,0,0);
    }
    #pragma unroll
    for (int a = 0; a < 2; a++) {
        #pragma unroll
        for (int b = 0; b < 2; b++) {
            int o = wn*32 + b*16 + l15;
            float bo = 0.3f*bcam[o] + 0.7f*bagg[o];
            #pragma unroll
            for (int rr = 0; rr < 4; rr++) {
                int r = r0 + wm*32 + a*16 + lk*4 + rr;
                if (r >= NB) continue;
                float val = acc[a][b][rr] + bo;
                Hdec[(size_t)r*64 + o] = val;
                Dn[(size_t)r*352 + 4 + o] = (f16)val;
                PTn[(size_t)((r & 31)*68 + 4 + o)*352 + (r >> 5)] = (f16)val;
            }
        }
    }
    {
        int r = r0 + (tid >> 2), q = tid & 3;
        if (r < NB) {
            Dn[(size_t)r*352 + q] = (f16)0.0f;
            PTn[(size_t)((r & 31)*68 + q)*352 + (r >> 5)] = (f16)0.0f;
        }
    }
}

__global__ void k_fc(const float* __restrict__ H, const float* __restrict__ Wfc,
                     const float* __restrict__ bfc, float* __restrict__ y,
                     f16* __restrict__ Dn, f16* __restrict__ PTn) {
    int idx = blockIdx.x*256 + threadIdx.x;
    if (idx >= NB*3) return;
    int o = idx % 3, r = idx / 3;
    float a = bfc[o];
    #pragma unroll 8
    for (int k = 0; k < 64; k++) a = fmaf(H[(size_t)r*64 + k], Wfc[k*3 + o], a);
    y[idx] = a;
    Dn[(size_t)r*352 + o] = (f16)a;
    PTn[(size_t)((r & 31)*68 + o)*352 + (r >> 5)] = (f16)a;
}

__global__ void k_out(const float* __restrict__ ys, float* __restrict__ out) {
    int idx = blockIdx.x*256 + threadIdx.x;
    if (idx >= BB*3*NN*12) return;
    int l = idx % 12;
    int n = (idx / 12) % NN;
    int o = (idx / (12*NN)) % 3;
    int b = idx / (12*NN*3);
    int q = o*12 + l;
    int t = q / 3, c = q % 3;
    out[idx] = ys[((size_t)t*NB + n*BB + b)*3 + c];
}

// ---------------- host ----------------
extern "C" void kernel_launch(void* const* d_in, const int* in_sizes, int n_in,
                              void* d_out, int out_size, void* d_ws, size_t ws_size,
                              hipStream_t stream) {
    const float* x      = (const float*)d_in[0];
    const float* st     = (const float*)d_in[1];
    const float* adj    = (const float*)d_in[2];
    const float* P      = (const float*)d_in[3];
    const float* H1_0   = (const float*)d_in[4];
    const float* H2_0   = (const float*)d_in[6];
    const float* W_encD = (const float*)d_in[8];
    const float* b_encD = (const float*)d_in[9];
    const float* W_encAD= (const float*)d_in[10];
    const float* b_encAD= (const float*)d_in[11];
    const float* W_dec  = (const float*)d_in[12];
    const float* b_dec  = (const float*)d_in[13];
    const float* W_fc   = (const float*)d_in[14];
    const float* b_fc   = (const float*)d_in[15];
    const float* W_aggH = (const float*)d_in[16];
    const float* b_aggH = (const float*)d_in[17];
    const float* W_camH = (const float*)d_in[20];
    const float* b_camH = (const float*)d_in[21];
    const float* wL     = (const float*)d_in[24];
    const float* bL     = (const float*)d_in[25];
    const float* wH     = (const float*)d_in[26];
    const float* bH     = (const float*)d_in[27];

    float* ws   = (float*)d_ws;
    float* G    = ws + OFF_G;
    float* rs   = ws + OFF_RS;
    float* cs   = rs + NN;
    float* rv   = ws + OFF_RV;
    float* Weff = ws + OFF_WEFF;
    f16*   Wt   = (f16*)(ws + OFF_WT);
    f16*   G16  = (f16*)(ws + OFF_G16);
    float* Mw   = ws + OFF_M;
    float* tv   = ws + OFF_TV;
    f16*   xs   = (f16*)(ws + OFF_XS);
    f16*   DP   = (f16*)(ws + OFF_DP);    // [e][buf][10400][352]
    f16*   PT   = (f16*)(ws + OFF_PT);    // [e][buf][2176][352]
    float* ZR   = ws + OFF_ZR;
    float* G2   = ZR;                      // alias: prep only
    float* Henc = ws + OFF_HENC;
    float* Hdec = ws + OFF_HDEC;
    float* ys   = ws + OFF_YS;

    // ---- prep ----
    k_sums<<<NN, 64, 0, stream>>>(adj, rs, cs);
    k_buildG<<<(NN*NN + 255)/256, 256, 0, stream>>>(adj, P, rs, cs, G);
    k_gg<<<dim3(11,11,2), 256, 0, stream>>>(G, G2);
    k_g16<<<(4*G16_MAT + 255)/256, 256, 0, stream>>>(G, G2, G16);
    k_rowsum<<<650, 64, 0, stream>>>(G, G2, rv);
    k_weff3<<<dim3(255,3), 256, 0, stream>>>(W_encD, b_encD, W_encAD, b_encAD,
                                             W_dec, b_dec, Weff);
    k_wt3<<<dim3((192*352 + 255)/256, 3), 256, 0, stream>>>(Weff, Wt);
    k_M3<<<dim3((325*192 + 255)/256, 3), 256, 0, stream>>>(Weff, rv, Mw);
    k_tv<<<3, 256, 0, stream>>>(st, tv);
    k_xs16<<<(2*TENC*NB*4 + 255)/256, 256, 0, stream>>>(x, xs);
    k_initH<<<(2*NB*64 + 255)/256, 256, 0, stream>>>(H1_0, H2_0, Henc);
    k_initDP<<<(2*NB*92 + 255)/256, 256, 0, stream>>>(xs, H1_0, H2_0, DP);
    k_initPT<<<(2*2176*352 + 255)/256, 256, 0, stream>>>(xs, H1_0, H2_0, PT);

    int par = 0;
    // ---- encoders (E=2) ----
    for (int t = 0; t < TENC; t++) {
        const f16* xn0 = (t < TENC-1) ? (xs + (size_t)(t+1)*NB*4) : nullptr;
        const f16* xn1 = (t < TENC-1) ? (xs + (size_t)(TENC + t+1)*NB*4) : nullptr;
        k_diffT<<<dim3(34,21,2), 256, 0, stream>>>(G16, PT + (size_t)par*PT_B,
                                                   DP + (size_t)par*DP_B);
        k_projT<0><<<dim3(2,163,2), 256, 0, stream>>>(Wt, WT_SET, Weff, WSET,
            Mw, M_SET, tv + (size_t)t*32,
            DP + (size_t)par*DP_B, DP + (size_t)(par^1)*DP_B, PT + (size_t)(par^1)*PT_B,
            ZR, Henc, nullptr, nullptr);
        par ^= 1;
        k_diffT<<<dim3(34,21,2), 256, 0, stream>>>(G16, PT + (size_t)par*PT_B,
                                                   DP + (size_t)par*DP_B);
        k_projT<1><<<dim3(1,163,2), 256, 0, stream>>>(Wt, WT_SET, Weff, WSET,
            Mw, M_SET, tv + (size_t)t*32,
            DP + (size_t)par*DP_B, DP + (size_t)(par^1)*DP_B, PT + (size_t)(par^1)*PT_B,
            ZR, Henc, xn0, xn1);
        par ^= 1;
    }

    // ---- fuse + decoder buf0 init (par == 0 here) ----
    k_fuse16<<<163, 256, 0, stream>>>(Henc, Henc + (size_t)NB*64,
                                      wL, bL, wH, bH, W_camH, b_camH, W_aggH, b_aggH,
                                      Hdec, DP, PT);

    // ---- decoder (E=1, weight set 2) ----
    for (int t = 0; t < TDEC; t++) {
        const float* tvt = tv + (size_t)(6 + t)*32;
        k_diffT<<<dim3(34,21,1), 256, 0, stream>>>(G16, PT + (size_t)par*PT_B,
                                                   DP + (size_t)par*DP_B);
        k_projT<0><<<dim3(2,163,1), 256, 0, stream>>>(Wt + 2*WT_SET, 0,
            Weff + 2*WSET, 0, Mw + 2*M_SET, 0, tvt,
            DP + (size_t)par*DP_B, DP + (size_t)(par^1)*DP_B, PT + (size_t)(par^1)*PT_B,
            ZR, Hdec, nullptr, nullptr);
        par ^= 1;
        k_diffT<<<dim3(34,21,1), 256, 0, stream>>>(G16, PT + (size_t)par*PT_B,
                                                   DP + (size_t)par*DP_B);
        k_projT<1><<<dim3(1,163,1), 256, 0, stream>>>(Wt + 2*WT_SET, 0,
            Weff + 2*WSET, 0, Mw + 2*M_SET, 0, tvt,
            DP + (size_t)par*DP_B, DP + (size_t)(par^1)*DP_B, PT + (size_t)(par^1)*PT_B,
            ZR, Hdec, nullptr, nullptr);
        par ^= 1;
        k_fc<<<(NB*3 + 255)/256, 256, 0, stream>>>(Hdec, W_fc, b_fc,
            ys + (size_t)t*NB*3, DP + (size_t)par*DP_B, PT + (size_t)par*PT_B);
    }

    k_out<<<(BB*3*NN*12 + 255)/256, 256, 0, stream>>>(ys, (float*)d_out);
}